// Round 1
// 228.952 us; speedup vs baseline: 1.0413x; 1.0413x over previous
//
#include <hip/hip_runtime.h>

// VACF via banded-Gram MFMA, round 10.
// G[t] = sum_i X[i][:] . X[i+t][:]  (t=0..99), X = [T=10000, C=3000] fp32.
//
// R9 was latency/occupancy-bound: MfmaUtil 2.6%, VALUBusy 6.9%, HBM 7.6%,
// Occupancy 28% -- grid was only 720 blocks = 2.8 blocks/CU (35% cap), so
// the per-iter sync->ds_write->sync->ds_read->MFMA latency chain was
// exposed (~8x issue cost). Fixes:
//  - KSPLIT 8 -> 24 (chunk-granular: 24 slices x 4 KB-chunks of 32 cols;
//    slice 23 has nit=2). Grid 90x24 = 2160 blocks = 8.4 blocks/CU.
//  - __launch_bounds__(256, 8): pin 8 blocks/CU (VGPR=60 fits <=64 budget;
//    LDS 15.8KB allows 10).
//  - XCD swizzle kept: xcd = blk&7, j = blk>>3; 3 k-slice sweeps per XCD,
//    consecutive j share 112/224 staged rows for L2 reuse.
//  - partial[] split into 8 per-XCD buckets to cut same-address atomic
//    serialization (2160 blocks x 100 lags).
// Everything else (MA=112, band staging, LPAD=34, register prefetch,
// diagonal-pair accumulators) unchanged from R9.

#define T_DIM 10000
#define C_DIM 3000
#define W 100
#define MA 112          // A rows per block
#define NA 7            // A subblocks of 16
#define SROWS 224       // staged rows (A + 112-row band)
#define NBB 90          // ceil(T_DIM / MA) -> covers 10080 rows (tail zeroed)
#define KSPLIT 24       // k-slices; slice owns CPB chunks of KB cols
#define CPB 4           // chunks per slice: 24*4*32 = 3072 >= 3000
#define KB 32           // cols per k-iter (MFMA K)
#define LPAD 34         // LDS row pitch in shorts
#define NPART 8         // per-XCD partial buckets

typedef __attribute__((ext_vector_type(8))) short short8;    // 8 bf16
typedef __attribute__((ext_vector_type(4))) short short4v;   // 4 bf16
typedef __attribute__((ext_vector_type(4))) float float4v;

__device__ __forceinline__ short f2bf(float f) {   // RNE fp32->bf16 (finite)
    unsigned u = __float_as_uint(f);
    u += 0x7fffu + ((u >> 16) & 1u);
    return (short)(u >> 16);
}

__global__ __launch_bounds__(256, 8)
void vacf_mfma(const float* __restrict__ X, float* __restrict__ partial) {
    const int tid  = threadIdx.x;
    const int lane = tid & 63;
    const int wv   = tid >> 6;
    const int xcd  = blockIdx.x & 7;           // XCD id (round-robin dispatch)
    const int j    = blockIdx.x >> 3;          // 0..269, consecutive on XCD
    const int ksix = xcd + 8 * (j / NBB);      // k-slice: XCD-constant per sweep
    const int bb   = j % NBB;                  // row-block: consecutive on XCD
    const int i0   = bb * MA;
    const int ks   = ksix * (CPB * KB);
    const int ke   = (ks + CPB * KB < C_DIM) ? (ks + CPB * KB) : C_DIM;
    const int nit  = (ke - ks + KB - 1) / KB;  // 4 (slice 23: 2)

    __shared__ short buf[SROWS * LPAD];        // 15.2 KB
    __shared__ float bins[W];
    if (tid < W) bins[tid] = 0.f;

    // staging map: thread -> (row r0 + 32s, cols 4cp..4cp+3), s = 0..6
    const int cp = tid & 7;
    const int r0 = tid >> 3;

    // fragment addressing
    const int n    = lane & 15;
    const int quad = lane >> 4;
    const int d0   = 2 * wv;                   // this wave's d-pair: d0, d0+1
    const short* fragbase = &buf[n * LPAD + quad * 8];

    float4v acc0 = {0.f, 0.f, 0.f, 0.f};
    float4v acc1 = {0.f, 0.f, 0.f, 0.f};
    float4v pf[NA];                            // 7 x float4 prefetch regs

    // prologue: load iteration 0 (k0==ks: cols always in range, all slices)
    {
        const int k0 = ks;
        #pragma unroll
        for (int s = 0; s < NA; ++s) {
            const int row = i0 + r0 + 32 * s;
            const int col = k0 + 4 * cp;
            if (row < T_DIM) {
                pf[s] = *(const float4v*)(X + (size_t)row * C_DIM + col);
            } else {
                pf[s] = (float4v){0.f, 0.f, 0.f, 0.f};
            }
        }
    }

    #pragma unroll 1
    for (int it = 0; it < nit; ++it) {
        __syncthreads();                       // prev ds_reads done (and bins init)

        // convert + stage current block
        #pragma unroll
        for (int s = 0; s < NA; ++s) {
            short4v o;
            o[0] = f2bf(pf[s][0]); o[1] = f2bf(pf[s][1]);
            o[2] = f2bf(pf[s][2]); o[3] = f2bf(pf[s][3]);
            *(short4v*)&buf[(r0 + 32 * s) * LPAD + 4 * cp] = o;
        }
        __syncthreads();                       // staging visible

        // prefetch next iteration (consumed after this iter's MFMA work)
        if (it + 1 < nit) {
            const int k0 = ks + (it + 1) * KB;
            const bool kfull = (k0 + KB <= ke);
            #pragma unroll
            for (int s = 0; s < NA; ++s) {
                const int row = i0 + r0 + 32 * s;
                const int col = k0 + 4 * cp;
                if ((row < T_DIM) & kfull) {
                    pf[s] = *(const float4v*)(X + (size_t)row * C_DIM + col);
                } else {
                    #pragma unroll
                    for (int e = 0; e < 4; ++e)
                        pf[s][e] = (row < T_DIM && col + e < ke)
                                     ? X[(size_t)row * C_DIM + col + e] : 0.f;
                }
            }
        }

        // fragments: A subblocks 0..6, B subblocks d0..d0+7
        short8 fa[NA], fb[8];
        #pragma unroll
        for (int a = 0; a < NA; ++a)
            fa[a] = *(const short8*)(fragbase + 16 * a * LPAD);
        #pragma unroll
        for (int u = 0; u < 8; ++u)
            fb[u] = *(const short8*)(fragbase + 16 * (d0 + u) * LPAD);

        // 14 MFMAs: acc0 sums tiles (a, d0), acc1 sums tiles (a, d0+1)
        #pragma unroll
        for (int a = 0; a < NA; ++a) {
            acc0 = __builtin_amdgcn_mfma_f32_16x16x32_bf16(fa[a], fb[a],     acc0, 0, 0, 0);
            acc1 = __builtin_amdgcn_mfma_f32_16x16x32_bf16(fa[a], fb[a + 1], acc1, 0, 0, 0);
        }
    }

    // epilogue: D[m][n] of diagonal d -> lag t = 16d + n - m  (m = quad*4 + p)
    #pragma unroll
    for (int p = 0; p < 4; ++p) {
        const int m  = quad * 4 + p;
        const int t0 = 16 * d0 + n - m;
        if (t0 >= 0 && t0 < W) atomicAdd(&bins[t0], acc0[p]);
        const int t1 = t0 + 16;
        if (t1 >= 0 && t1 < W) atomicAdd(&bins[t1], acc1[p]);
    }
    __syncthreads();
    if (tid < W) atomicAdd(&partial[xcd * W + tid], bins[tid]);
}

__global__ void vacf_scale(const float* __restrict__ partial, float* __restrict__ out) {
    int t = threadIdx.x;
    if (t < W) {
        float s = 0.f;
        #pragma unroll
        for (int b = 0; b < NPART; ++b) s += partial[b * W + t];
        out[t] = s / ((float)(T_DIM - t) * (float)C_DIM);
    }
}

extern "C" void kernel_launch(void* const* d_in, const int* in_sizes, int n_in,
                              void* d_out, int out_size, void* d_ws, size_t ws_size,
                              hipStream_t stream) {
    const float* X = (const float*)d_in[0];
    float* out = (float*)d_out;
    float* ws  = (float*)d_ws;

    hipMemsetAsync(ws, 0, NPART * W * sizeof(float), stream);
    vacf_mfma<<<NBB * KSPLIT, 256, 0, stream>>>(X, ws);
    vacf_scale<<<1, 128, 0, stream>>>(ws, out);
}

// Round 2
// 214.205 us; speedup vs baseline: 1.1130x; 1.0688x over previous
//
#include <hip/hip_runtime.h>

// VACF via banded-Gram MFMA, round 11.
// G[t] = sum_i X[i][:] . X[i+t][:]  (t=0..99), X = [T=10000, C=3000] fp32.
//
// R10 post-mortem: occupancy 28->64%, VGPR 60->32 (launch_bounds(256,8)
// spilled: WRITE 292KB->3MB), duration UNCHANGED (111->108us); one dispatch
// ran fully L3-resident (3MB fetch) at the same 110us. => not HBM-bound,
// not occupancy-bound: per-iteration exposed load latency serialized by the
// load->barrier->ds_write->barrier convoy, MLP capped by the register
// round-trip. Fix: m97-style async pipeline.
//  - global_load_lds (16B) stages raw fp32 into double-buffered LDS,
//    prefetch depth 1, counted s_waitcnt vmcnt(7) + raw s_barrier (prefetch
//    never drained; __syncthreads would vmcnt(0)).
//  - LDS slot swizzle (16B slot ^= row&7 within 128B rows) applied on the
//    GLOBAL source address (gload_lds dest must be linear) and on the
//    read side -> conflict-free stride-128B fragment reads.
//  - fp32->bf16 conversion moved to fragment read (register side).
//  - fast path guard-free (nit=4 compile-time); tail blocks (bb>=88 or
//    ksix==23, 136 of 2160) keep the R10 register-staging path.
//  - LDS 2x28.7KB -> 2 blocks/CU; launch_bounds(256,2) => 128 VGPR budget.

#define T_DIM 10000
#define C_DIM 3000
#define W 100
#define MA 112          // A rows per block
#define NA 7            // A subblocks of 16
#define SROWS 224       // staged rows (A + 112-row band)
#define NBB 90          // ceil(T_DIM / MA)
#define KSPLIT 24       // k-slices
#define CPB 4           // 32-col chunks per slice: 24*4*32 = 3072 >= 3000
#define KB 32           // cols per k-iter (MFMA K)
#define LPAD 34         // slow-path LDS row pitch in shorts
#define NPART 8         // per-XCD partial buckets
#define BUFB (SROWS * KB * 4)   // 28672 B per fp32 buffer

typedef __attribute__((ext_vector_type(8))) short short8;    // 8 bf16
typedef __attribute__((ext_vector_type(4))) short short4v;   // 4 bf16
typedef __attribute__((ext_vector_type(4))) float float4v;

__device__ __forceinline__ short f2bf(float f) {   // RNE fp32->bf16 (finite)
    unsigned u = __float_as_uint(f);
    u += 0x7fffu + ((u >> 16) & 1u);
    return (short)(u >> 16);
}

__device__ __forceinline__ void gload_lds16(const float* src, char* dst) {
    __builtin_amdgcn_global_load_lds(
        (const __attribute__((address_space(1))) float*)src,
        (__attribute__((address_space(3))) float*)dst, 16, 0, 0);
}

// read one 16x32 tile fragment (8 fp32 -> 8 bf16) from swizzled fp32 LDS
__device__ __forceinline__ short8 ldfrag(const char* lbase, int row, int q) {
    const int off = row * 128 + ((q * 32) ^ ((row & 7) << 4));
    const float4v u0 = *(const float4v*)(lbase + off);
    const float4v u1 = *(const float4v*)(lbase + (off ^ 16));
    short8 r;
    r[0] = f2bf(u0[0]); r[1] = f2bf(u0[1]); r[2] = f2bf(u0[2]); r[3] = f2bf(u0[3]);
    r[4] = f2bf(u1[0]); r[5] = f2bf(u1[1]); r[6] = f2bf(u1[2]); r[7] = f2bf(u1[3]);
    return r;
}

__global__ __launch_bounds__(256, 2)
void vacf_mfma(const float* __restrict__ X, float* __restrict__ partial) {
    const int tid  = threadIdx.x;
    const int lane = tid & 63;
    const int wv   = tid >> 6;
    const int xcd  = blockIdx.x & 7;           // XCD id (round-robin dispatch)
    const int j    = blockIdx.x >> 3;          // consecutive on XCD
    const int ksix = xcd + 8 * (j / NBB);      // k-slice: XCD-constant per sweep
    const int bb   = j % NBB;                  // row-block: consecutive on XCD
    const int i0   = bb * MA;
    const int ks   = ksix * (CPB * KB);

    __shared__ __align__(16) char lds[2 * BUFB];   // 57.3 KB (aliased by slow path)
    __shared__ float bins[W];
    if (tid < W) bins[tid] = 0.f;

    // fragment addressing
    const int n    = lane & 15;
    const int quad = lane >> 4;
    const int d0   = 2 * wv;                   // this wave's d-pair: d0, d0+1

    float4v acc0 = {0.f, 0.f, 0.f, 0.f};
    float4v acc1 = {0.f, 0.f, 0.f, 0.f};

    const bool fast = (i0 + SROWS <= T_DIM) && (ksix < KSPLIT - 1);

    if (fast) {
        // ---------------- fast path: async gload_lds double-buffer ----------
        // staging map: wave wv stages rows 56*wv .. 56*wv+55, 7 chunks of 8
        // rows; lane -> (row lr = lane>>3 within chunk, dest slot lane&7).
        const int lr = lane >> 3;
        const int lg = lane & 7;

        // per-lane source row/col (col gets the slot-swizzle XOR)
        // chunk m: r_local = 56*wv + 8*m + lr
        #define STAGE(bi, k0)                                                    \
            {                                                                    \
                char* lb = lds + (bi) * BUFB + 56 * wv * 128;                    \
                _Pragma("unroll")                                                \
                for (int m = 0; m < 7; ++m) {                                    \
                    const int rl = 56 * wv + 8 * m + lr;                         \
                    const float* src = X + (size_t)(i0 + rl) * C_DIM + (k0)      \
                                         + 4 * (lg ^ (rl & 7));                  \
                    gload_lds16(src, lb + m * 1024);                             \
                }                                                                \
            }

        STAGE(0, ks)                           // prologue: buffer 0 in flight

        #pragma unroll
        for (int it = 0; it < CPB; ++it) {
            const int cur = it & 1;
            if (it + 1 < CPB) {
                STAGE(cur ^ 1, ks + (it + 1) * KB)   // prefetch next buffer
                asm volatile("s_waitcnt vmcnt(7)" ::: "memory");  // cur done
            } else {
                asm volatile("s_waitcnt vmcnt(0)" ::: "memory");
            }
            __builtin_amdgcn_s_barrier();      // all waves' cur chunks done

            const char* lbase = lds + cur * BUFB;
            short8 fa[NA], fb[8];
            #pragma unroll
            for (int a = 0; a < NA; ++a)
                fa[a] = ldfrag(lbase, 16 * a + n, quad);
            #pragma unroll
            for (int u = 0; u < 8; ++u)
                fb[u] = ldfrag(lbase, 16 * (d0 + u) + n, quad);

            #pragma unroll
            for (int a = 0; a < NA; ++a) {
                acc0 = __builtin_amdgcn_mfma_f32_16x16x32_bf16(fa[a], fb[a],     acc0, 0, 0, 0);
                acc1 = __builtin_amdgcn_mfma_f32_16x16x32_bf16(fa[a], fb[a + 1], acc1, 0, 0, 0);
            }

            __builtin_amdgcn_sched_barrier(0); // keep reads on this side
            __builtin_amdgcn_s_barrier();      // reads done -> cur reusable
        }
        #undef STAGE
    } else {
        // ---------------- slow path: R10 register staging (tail blocks) -----
        short* buf = (short*)lds;              // [SROWS][LPAD]
        const int ke  = (ks + CPB * KB < C_DIM) ? (ks + CPB * KB) : C_DIM;
        const int nit = (ke - ks + KB - 1) / KB;
        const int cp  = tid & 7;
        const int r0  = tid >> 3;
        const short* fragbase = &buf[n * LPAD + quad * 8];
        float4v pf[NA];

        {
            const int k0 = ks;
            #pragma unroll
            for (int s = 0; s < NA; ++s) {
                const int row = i0 + r0 + 32 * s;
                const int col = k0 + 4 * cp;
                if (row < T_DIM) {
                    pf[s] = *(const float4v*)(X + (size_t)row * C_DIM + col);
                } else {
                    pf[s] = (float4v){0.f, 0.f, 0.f, 0.f};
                }
            }
        }

        #pragma unroll 1
        for (int it = 0; it < nit; ++it) {
            __syncthreads();
            #pragma unroll
            for (int s = 0; s < NA; ++s) {
                short4v o;
                o[0] = f2bf(pf[s][0]); o[1] = f2bf(pf[s][1]);
                o[2] = f2bf(pf[s][2]); o[3] = f2bf(pf[s][3]);
                *(short4v*)&buf[(r0 + 32 * s) * LPAD + 4 * cp] = o;
            }
            __syncthreads();

            if (it + 1 < nit) {
                const int k0 = ks + (it + 1) * KB;
                const bool kfull = (k0 + KB <= ke);
                #pragma unroll
                for (int s = 0; s < NA; ++s) {
                    const int row = i0 + r0 + 32 * s;
                    const int col = k0 + 4 * cp;
                    if ((row < T_DIM) & kfull) {
                        pf[s] = *(const float4v*)(X + (size_t)row * C_DIM + col);
                    } else {
                        #pragma unroll
                        for (int e = 0; e < 4; ++e)
                            pf[s][e] = (row < T_DIM && col + e < ke)
                                         ? X[(size_t)row * C_DIM + col + e] : 0.f;
                    }
                }
            }

            short8 fa[NA], fb[8];
            #pragma unroll
            for (int a = 0; a < NA; ++a)
                fa[a] = *(const short8*)(fragbase + 16 * a * LPAD);
            #pragma unroll
            for (int u = 0; u < 8; ++u)
                fb[u] = *(const short8*)(fragbase + 16 * (d0 + u) * LPAD);

            #pragma unroll
            for (int a = 0; a < NA; ++a) {
                acc0 = __builtin_amdgcn_mfma_f32_16x16x32_bf16(fa[a], fb[a],     acc0, 0, 0, 0);
                acc1 = __builtin_amdgcn_mfma_f32_16x16x32_bf16(fa[a], fb[a + 1], acc1, 0, 0, 0);
            }
        }
        __syncthreads();                       // protect bins (epilogue next)
    }

    // epilogue: D[m][n] of diagonal d -> lag t = 16d + n - m  (m = quad*4 + p)
    #pragma unroll
    for (int p = 0; p < 4; ++p) {
        const int m  = quad * 4 + p;
        const int t0 = 16 * d0 + n - m;
        if (t0 >= 0 && t0 < W) atomicAdd(&bins[t0], acc0[p]);
        const int t1 = t0 + 16;
        if (t1 >= 0 && t1 < W) atomicAdd(&bins[t1], acc1[p]);
    }
    __syncthreads();
    if (tid < W) atomicAdd(&partial[xcd * W + tid], bins[tid]);
}

__global__ void vacf_scale(const float* __restrict__ partial, float* __restrict__ out) {
    int t = threadIdx.x;
    if (t < W) {
        float s = 0.f;
        #pragma unroll
        for (int b = 0; b < NPART; ++b) s += partial[b * W + t];
        out[t] = s / ((float)(T_DIM - t) * (float)C_DIM);
    }
}

extern "C" void kernel_launch(void* const* d_in, const int* in_sizes, int n_in,
                              void* d_out, int out_size, void* d_ws, size_t ws_size,
                              hipStream_t stream) {
    const float* X = (const float*)d_in[0];
    float* out = (float*)d_out;
    float* ws  = (float*)d_ws;

    hipMemsetAsync(ws, 0, NPART * W * sizeof(float), stream);
    vacf_mfma<<<NBB * KSPLIT, 256, 0, stream>>>(X, ws);
    vacf_scale<<<1, 128, 0, stream>>>(ws, out);
}

// Round 3
// 210.875 us; speedup vs baseline: 1.1305x; 1.0158x over previous
//
#include <hip/hip_runtime.h>

// VACF via banded-Gram MFMA, round 12.
// G[t] = sum_i X[i][:] . X[i+t][:]  (t=0..99), X = [T=10000, C=3000] fp32.
//
// R9-R11 post-mortem: three structurally disjoint kernels (reg-staging
// @2.8 blk/CU, reg-staging @8 blk/CU, async gload_lds dbuf @2 blk/CU) all
// ran 108-113us with all pipes idle. Invariant: staging-read BW pinned at
// 2.0-2.3 TB/s regardless of occupancy/MLP/L3-residency. Shared pattern:
// every staging wave-instr touches 8 scattered 128-B row segments (rows
// 12KB apart). Theory: per-instruction segment fan-out wall on TA->L2/L3.
// Fix: one-shot relayout X -> Y bf16 chunk-major (Y[c][r][32cols], 64-B
// granules, rows padded to 10368, chunks to 96, LDS-bank swizzle
// sigma(r)=(r>>1)&3 pre-baked into granule slot order). Main kernel then
// stages 1-KiB FULLY CONTIGUOUS gload_lds (1 segment/instr vs 8):
//  - traffic 240 -> 94 MB (bf16 + MA=256: amplification 384/256=1.5)
//  - per-iter fp32->bf16 VALU conversion eliminated
//  - fragment ds_read_b128 2-way max via sigma swizzle (free, m136)
//  - MA=256/NA=16, SROWS=384, KSPLIT=16, CPB=6; LDS 2x24KB -> 3 blk/CU
// Y lives in d_ws (61 MB); if ws_size too small, fall back to the proven
// R10 register-staging kernel.

#define T_DIM 10000
#define C_DIM 3000
#define W 100

// relayout geometry
#define CHUNKS 96            // 32-col chunks (3000 -> 94 -> pad to 96)
#define RPAD 10368           // padded rows (max staged row 9984+384)
#define GRAN 64              // bytes per (chunk,row) granule = 32 bf16
#define YOFF 4096            // Y offset in ws; partial[] at ws+0
#define WS_NEED (YOFF + (size_t)CHUNKS * RPAD * GRAN)

// main kernel geometry
#define MA 256               // A rows per block
#define NA 16                // A subblocks of 16
#define SROWS 384            // staged rows (A + band to subblock 23)
#define NBB 40               // 40*256 = 10240 >= 10000
#define KSPLIT 16
#define CPB 6                // chunks per k-slice: 16*6 = 96
#define TILEB (SROWS * GRAN) // 24576 B per buffer
#define NPART 8

// fallback (R10) geometry
#define FB_MA 112
#define FB_NA 7
#define FB_SROWS 224
#define FB_NBB 90
#define FB_KSPLIT 24
#define FB_CPB 4
#define FB_KB 32
#define FB_LPAD 34

typedef __attribute__((ext_vector_type(8))) short short8;    // 8 bf16
typedef __attribute__((ext_vector_type(4))) short short4v;   // 4 bf16
typedef __attribute__((ext_vector_type(4))) float float4v;
typedef __attribute__((ext_vector_type(4))) unsigned int uint4v;

__device__ __forceinline__ short f2bf(float f) {   // RNE fp32->bf16 (finite)
    unsigned u = __float_as_uint(f);
    u += 0x7fffu + ((u >> 16) & 1u);
    return (short)(u >> 16);
}

__device__ __forceinline__ void gload_lds16(const char* src, char* dst) {
    __builtin_amdgcn_global_load_lds(
        (const __attribute__((address_space(1))) unsigned int*)src,
        (__attribute__((address_space(3))) unsigned int*)dst, 16, 0, 0);
}

// ---------------------------------------------------------------------------
// Kernel 1: X fp32 row-major -> Y bf16 chunk-major with baked sigma swizzle.
// Granule (c, r) holds cols 32c + 8*(p ^ sigma(r)) .. +7 at slot position p,
// sigma(r) = (r>>1)&3. Zero outside [0,10000) x [0,3000).
// Block: 64 rows x 256 cols, LDS transpose (pitch 528 B kills phase-2
// 64-way conflicts down to 8-way; pass is HBM-bound anyway).
// ---------------------------------------------------------------------------
__global__ __launch_bounds__(256)
void vacf_relayout(const float* __restrict__ X, char* __restrict__ Y) {
    __shared__ char tile[64 * 528];
    const int tid = threadIdx.x;
    const int bc  = blockIdx.x % 12;       // col-group (256 cols)
    const int br  = blockIdx.x / 12;       // row-group (64 rows)
    const int r0  = br * 64;
    const int c0  = bc * 256;

    // phase 1: coalesced read of X[64r x 256c], convert, swizzled LDS store.
    #pragma unroll
    for (int k = 0; k < 16; ++k) {
        const int rl  = k * 4 + (tid >> 6);
        const int col = (tid & 63) * 4;
        const int row = r0 + rl;
        float4v v = {0.f, 0.f, 0.f, 0.f};
        if (row < T_DIM && c0 + col + 4 <= C_DIM)   // 3000-2816=184, %4==0: no straddle
            v = *(const float4v*)(X + (size_t)row * C_DIM + c0 + col);
        short4v o;
        o[0] = f2bf(v[0]); o[1] = f2bf(v[1]); o[2] = f2bf(v[2]); o[3] = f2bf(v[3]);
        const int cc = col >> 5, p = (col >> 3) & 3, sub = col & 7;
        const int ps = p ^ ((rl >> 1) & 3);        // r0 mult of 64 -> sigma local
        *(short4v*)&tile[rl * 528 + cc * 64 + ps * 16 + sub * 2] = o;
    }
    __syncthreads();

    // phase 2: write out 8 chunks x 64 rows of 64-B granules, coalesced in r.
    #pragma unroll
    for (int pass = 0; pass < 2; ++pass) {
        const int g  = pass * 256 + tid;
        const int cc = g >> 6, rl = g & 63;
        char* dst = Y + ((size_t)(bc * 8 + cc) * RPAD + r0 + rl) * GRAN;
        const char* s = &tile[rl * 528 + cc * 64];
        #pragma unroll
        for (int q = 0; q < 4; ++q)
            *(uint4v*)(dst + q * 16) = *(const uint4v*)(s + q * 16);
    }
}

// ---------------------------------------------------------------------------
// Kernel 2: banded-Gram MFMA from chunk-major Y. Contiguous 1-KiB staging.
// ---------------------------------------------------------------------------
__global__ __launch_bounds__(256, 3)
void vacf_main(const char* __restrict__ Y, float* __restrict__ partial) {
    const int tid  = threadIdx.x;
    const int lane = tid & 63;
    const int wv   = tid >> 6;
    const int xcd  = blockIdx.x & 7;
    const int j    = blockIdx.x >> 3;          // 0..79, consecutive on XCD
    const int ksix = xcd + 8 * (j / NBB);      // k-slice, XCD-constant per sweep
    const int bb   = j % NBB;                  // row-block, consecutive on XCD
    const int i0   = bb * MA;                  // mult of 256 -> sigma uses local row

    __shared__ __align__(16) char lds[2 * TILEB];   // 48 KB
    __shared__ float bins[W];
    if (tid < W) bins[tid] = 0.f;

    const int n    = lane & 15;
    const int quad = lane >> 4;
    const int d0   = 2 * wv;                   // wave's diagonal pair d0, d0+1
    // per-lane fragment base: row n, slot quad ^ sigma(n); tile row R=16s+n
    // adds s*1024. sigma(16s+n) == (n>>1)&3 because 8s % 4 == 0.
    const int fragoff = n * 64 + ((quad ^ ((n >> 1) & 3)) << 4);
    const int lr16 = lane * 16;

    float4v acc0 = {0.f, 0.f, 0.f, 0.f};
    float4v acc1 = {0.f, 0.f, 0.f, 0.f};

    // staging: wave wv owns rows [wv*96, wv*96+96); 6 x 1-KiB contiguous DMA
    #define STAGE(bi, cix)                                                     \
        {                                                                      \
            const char* sb = Y + ((size_t)(cix) * RPAD + i0 + wv * 96) * GRAN; \
            char* db = lds + (bi) * TILEB + wv * 96 * GRAN;                    \
            _Pragma("unroll")                                                  \
            for (int m = 0; m < 6; ++m)                                        \
                gload_lds16(sb + m * 1024 + lr16, db + m * 1024);              \
        }

    STAGE(0, ksix * CPB)                       // prologue

    #pragma unroll
    for (int it = 0; it < CPB; ++it) {
        const int cur = it & 1;
        if (it + 1 < CPB) {
            STAGE(cur ^ 1, ksix * CPB + it + 1)          // prefetch next
            asm volatile("s_waitcnt vmcnt(6)" ::: "memory");  // cur done
        } else {
            asm volatile("s_waitcnt vmcnt(0)" ::: "memory");
        }
        __builtin_amdgcn_s_barrier();          // all waves' cur tile ready

        const char* lb = lds + cur * TILEB + fragoff;
        short8 fbp = *(const short8*)(lb + d0 * 1024);       // B subblock d0
        #pragma unroll
        for (int a = 0; a < NA; ++a) {
            const short8 fav = *(const short8*)(lb + a * 1024);
            const short8 fbn = *(const short8*)(lb + (d0 + a + 1) * 1024);
            acc0 = __builtin_amdgcn_mfma_f32_16x16x32_bf16(fav, fbp, acc0, 0, 0, 0);
            acc1 = __builtin_amdgcn_mfma_f32_16x16x32_bf16(fav, fbn, acc1, 0, 0, 0);
            fbp = fbn;
        }

        __builtin_amdgcn_sched_barrier(0);     // reads stay on this side
        __builtin_amdgcn_s_barrier();          // cur reusable
    }
    #undef STAGE

    // epilogue: D[m][n] of diagonal d -> lag t = 16d + n - m  (m = quad*4 + p)
    #pragma unroll
    for (int p = 0; p < 4; ++p) {
        const int m  = quad * 4 + p;
        const int t0 = 16 * d0 + n - m;
        if (t0 >= 0 && t0 < W) atomicAdd(&bins[t0], acc0[p]);
        const int t1 = t0 + 16;
        if (t1 >= 0 && t1 < W) atomicAdd(&bins[t1], acc1[p]);
    }
    __syncthreads();
    if (tid < W) atomicAdd(&partial[xcd * W + tid], bins[tid]);
}

// ---------------------------------------------------------------------------
// Fallback (ws too small): R10 register-staging kernel, proven correct.
// ---------------------------------------------------------------------------
__global__ __launch_bounds__(256, 2)
void vacf_fb(const float* __restrict__ X, float* __restrict__ partial) {
    const int tid  = threadIdx.x;
    const int lane = tid & 63;
    const int wv   = tid >> 6;
    const int xcd  = blockIdx.x & 7;
    const int j    = blockIdx.x >> 3;
    const int ksix = xcd + 8 * (j / FB_NBB);
    const int bb   = j % FB_NBB;
    const int i0   = bb * FB_MA;
    const int ks   = ksix * (FB_CPB * FB_KB);
    const int ke   = (ks + FB_CPB * FB_KB < C_DIM) ? (ks + FB_CPB * FB_KB) : C_DIM;
    const int nit  = (ke - ks + FB_KB - 1) / FB_KB;

    __shared__ short buf[FB_SROWS * FB_LPAD];
    __shared__ float bins[W];
    if (tid < W) bins[tid] = 0.f;

    const int cp = tid & 7;
    const int r0 = tid >> 3;
    const int n    = lane & 15;
    const int quad = lane >> 4;
    const int d0   = 2 * wv;
    const short* fragbase = &buf[n * FB_LPAD + quad * 8];

    float4v acc0 = {0.f, 0.f, 0.f, 0.f};
    float4v acc1 = {0.f, 0.f, 0.f, 0.f};
    float4v pf[FB_NA];

    {
        #pragma unroll
        for (int s = 0; s < FB_NA; ++s) {
            const int row = i0 + r0 + 32 * s;
            const int col = ks + 4 * cp;
            pf[s] = (row < T_DIM) ? *(const float4v*)(X + (size_t)row * C_DIM + col)
                                  : (float4v){0.f, 0.f, 0.f, 0.f};
        }
    }

    #pragma unroll 1
    for (int it = 0; it < nit; ++it) {
        __syncthreads();
        #pragma unroll
        for (int s = 0; s < FB_NA; ++s) {
            short4v o;
            o[0] = f2bf(pf[s][0]); o[1] = f2bf(pf[s][1]);
            o[2] = f2bf(pf[s][2]); o[3] = f2bf(pf[s][3]);
            *(short4v*)&buf[(r0 + 32 * s) * FB_LPAD + 4 * cp] = o;
        }
        __syncthreads();

        if (it + 1 < nit) {
            const int k0 = ks + (it + 1) * FB_KB;
            const bool kfull = (k0 + FB_KB <= ke);
            #pragma unroll
            for (int s = 0; s < FB_NA; ++s) {
                const int row = i0 + r0 + 32 * s;
                const int col = k0 + 4 * cp;
                if ((row < T_DIM) & kfull) {
                    pf[s] = *(const float4v*)(X + (size_t)row * C_DIM + col);
                } else {
                    #pragma unroll
                    for (int e = 0; e < 4; ++e)
                        pf[s][e] = (row < T_DIM && col + e < ke)
                                     ? X[(size_t)row * C_DIM + col + e] : 0.f;
                }
            }
        }

        short8 fa[FB_NA], fb[8];
        #pragma unroll
        for (int a = 0; a < FB_NA; ++a)
            fa[a] = *(const short8*)(fragbase + 16 * a * FB_LPAD);
        #pragma unroll
        for (int u = 0; u < 8; ++u)
            fb[u] = *(const short8*)(fragbase + 16 * (d0 + u) * FB_LPAD);

        #pragma unroll
        for (int a = 0; a < FB_NA; ++a) {
            acc0 = __builtin_amdgcn_mfma_f32_16x16x32_bf16(fa[a], fb[a],     acc0, 0, 0, 0);
            acc1 = __builtin_amdgcn_mfma_f32_16x16x32_bf16(fa[a], fb[a + 1], acc1, 0, 0, 0);
        }
    }

    #pragma unroll
    for (int p = 0; p < 4; ++p) {
        const int m  = quad * 4 + p;
        const int t0 = 16 * d0 + n - m;
        if (t0 >= 0 && t0 < W) atomicAdd(&bins[t0], acc0[p]);
        const int t1 = t0 + 16;
        if (t1 >= 0 && t1 < W) atomicAdd(&bins[t1], acc1[p]);
    }
    __syncthreads();
    if (tid < W) atomicAdd(&partial[xcd * W + tid], bins[tid]);
}

__global__ void vacf_scale(const float* __restrict__ partial, float* __restrict__ out) {
    int t = threadIdx.x;
    if (t < W) {
        float s = 0.f;
        #pragma unroll
        for (int b = 0; b < NPART; ++b) s += partial[b * W + t];
        out[t] = s / ((float)(T_DIM - t) * (float)C_DIM);
    }
}

extern "C" void kernel_launch(void* const* d_in, const int* in_sizes, int n_in,
                              void* d_out, int out_size, void* d_ws, size_t ws_size,
                              hipStream_t stream) {
    const float* X = (const float*)d_in[0];
    float* out = (float*)d_out;
    float* ws  = (float*)d_ws;

    hipMemsetAsync(ws, 0, NPART * W * sizeof(float), stream);
    if (ws_size >= WS_NEED) {
        char* Y = (char*)d_ws + YOFF;
        vacf_relayout<<<(RPAD / 64) * 12, 256, 0, stream>>>(X, Y);
        vacf_main<<<NBB * KSPLIT, 256, 0, stream>>>(Y, ws);
    } else {
        vacf_fb<<<FB_NBB * FB_KSPLIT, 256, 0, stream>>>(X, ws);
    }
    vacf_scale<<<1, 128, 0, stream>>>(ws, out);
}

// Round 4
// 203.635 us; speedup vs baseline: 1.1707x; 1.0356x over previous
//
#include <hip/hip_runtime.h>

// VACF via banded-Gram MFMA, round 13.
// G[t] = sum_i X[i][:] . X[i+t][:]  (t=0..99), X = [T=10000, C=3000] fp32.
//
// R12 post-mortem: contiguous-staging theory CONFIRMED -- vacf_main dropped
// out of top-5 (<70us, was 113us). New top cost we control: vacf_relayout
// 69.9us at only 2.6 TB/s effective (same machine streams 6.9 TB/s on the
// harness fills). Static diagnosis:
//  (a) phase-2 global stores were 4x q-strided 16B/lane at 64B stride ->
//      4x write-request amplification (same fan-out disease R12 cured on
//      the read side);
//  (b) phase-2 LDS pitch 528B == 4 words (mod 32) -> ~8-way ds_read_b128
//      bank conflicts.
// R13 fixes (relayout ONLY; vacf_main bit-identical to R12 so per-dispatch
// counters stay interpretable):
//  - phase 2 lane map (rl = w*16 + (l>>2), q = l&3): every wave-store is
//    1 KiB fully contiguous in Y (1 segment/instr);
//  - tile pitch 576B (144w == 16 mod 32): quarter-wave b128 reads hit the
//    inherent 2 words/bank exactly (conflict-free);
//  - phase-1 LDS writes remain a bijective permutation of a contiguous
//    512B span per wave (no extra conflicts).
// Y layout (chunk-major 64B granules, sigma(r)=(r>>1)&3 baked) unchanged.

#define T_DIM 10000
#define C_DIM 3000
#define W 100

// relayout geometry
#define CHUNKS 96            // 32-col chunks (3000 -> 94 -> pad to 96)
#define RPAD 10368           // padded rows (max staged row 9984+384)
#define GRAN 64              // bytes per (chunk,row) granule = 32 bf16
#define PITCH 576            // relayout LDS tile pitch (bytes); 144w==16 mod 32
#define YOFF 4096            // Y offset in ws; partial[] at ws+0
#define WS_NEED (YOFF + (size_t)CHUNKS * RPAD * GRAN)

// main kernel geometry
#define MA 256               // A rows per block
#define NA 16                // A subblocks of 16
#define SROWS 384            // staged rows (A + band to subblock 23)
#define NBB 40               // 40*256 = 10240 >= 10000
#define KSPLIT 16
#define CPB 6                // chunks per k-slice: 16*6 = 96
#define TILEB (SROWS * GRAN) // 24576 B per buffer
#define NPART 8

// fallback (R10) geometry
#define FB_MA 112
#define FB_NA 7
#define FB_SROWS 224
#define FB_NBB 90
#define FB_KSPLIT 24
#define FB_CPB 4
#define FB_KB 32
#define FB_LPAD 34

typedef __attribute__((ext_vector_type(8))) short short8;    // 8 bf16
typedef __attribute__((ext_vector_type(4))) short short4v;   // 4 bf16
typedef __attribute__((ext_vector_type(4))) float float4v;
typedef __attribute__((ext_vector_type(4))) unsigned int uint4v;

__device__ __forceinline__ short f2bf(float f) {   // RNE fp32->bf16 (finite)
    unsigned u = __float_as_uint(f);
    u += 0x7fffu + ((u >> 16) & 1u);
    return (short)(u >> 16);
}

__device__ __forceinline__ void gload_lds16(const char* src, char* dst) {
    __builtin_amdgcn_global_load_lds(
        (const __attribute__((address_space(1))) unsigned int*)src,
        (__attribute__((address_space(3))) unsigned int*)dst, 16, 0, 0);
}

// ---------------------------------------------------------------------------
// Kernel 1: X fp32 row-major -> Y bf16 chunk-major with baked sigma swizzle.
// Granule (c, r) holds cols 32c + 8*(p ^ sigma(r)) .. +7 at slot position p,
// sigma(r) = (r>>1)&3. Zero outside [0,10000) x [0,3000).
// Block: 64 rows x 256 cols.
// ---------------------------------------------------------------------------
__global__ __launch_bounds__(256)
void vacf_relayout(const float* __restrict__ X, char* __restrict__ Y) {
    __shared__ __align__(16) char tile[64 * PITCH];   // 36.9 KB
    const int tid = threadIdx.x;
    const int l   = tid & 63;
    const int w   = tid >> 6;
    const int bc  = blockIdx.x % 12;       // col-group (256 cols)
    const int br  = blockIdx.x / 12;       // row-group (64 rows)
    const int r0  = br * 64;
    const int c0  = bc * 256;

    // phase 1: coalesced read of X[64r x 256c], convert, swizzled LDS store.
    // wave w, iter k: row rl = k*4 + w, lane covers cols 4l..4l+3 (1KB/wave).
    #pragma unroll
    for (int k = 0; k < 16; ++k) {
        const int rl  = k * 4 + w;
        const int col = l * 4;
        const int row = r0 + rl;
        float4v v = {0.f, 0.f, 0.f, 0.f};
        if (row < T_DIM && c0 + col + 4 <= C_DIM)   // 3000-2816=184, %4==0: no straddle
            v = *(const float4v*)(X + (size_t)row * C_DIM + c0 + col);
        short4v o;
        o[0] = f2bf(v[0]); o[1] = f2bf(v[1]); o[2] = f2bf(v[2]); o[3] = f2bf(v[3]);
        const int cc = col >> 5, p = (col >> 3) & 3, sub = col & 7;
        const int ps = p ^ ((rl >> 1) & 3);        // r0 mult of 64 -> sigma local
        *(short4v*)&tile[rl * PITCH + cc * 64 + ps * 16 + sub * 2] = o;
    }
    __syncthreads();

    // phase 2: wave w owns rows [16w, 16w+16); for each chunk cc, lane
    // (rl = 16w + (l>>2), q = l&3) reads 16B from LDS and stores into a
    // fully contiguous 1KB span of Y (granules are row-consecutive).
    const int rl = 16 * w + (l >> 2);
    const int q  = l & 3;
    const char* s = &tile[rl * PITCH + q * 16];
    #pragma unroll
    for (int cc = 0; cc < 8; ++cc) {
        char* dst = Y + ((size_t)(bc * 8 + cc) * RPAD + r0 + rl) * GRAN + q * 16;
        *(uint4v*)dst = *(const uint4v*)(s + cc * 64);
    }
}

// ---------------------------------------------------------------------------
// Kernel 2: banded-Gram MFMA from chunk-major Y. Contiguous 1-KiB staging.
// (bit-identical to R12)
// ---------------------------------------------------------------------------
__global__ __launch_bounds__(256, 3)
void vacf_main(const char* __restrict__ Y, float* __restrict__ partial) {
    const int tid  = threadIdx.x;
    const int lane = tid & 63;
    const int wv   = tid >> 6;
    const int xcd  = blockIdx.x & 7;
    const int j    = blockIdx.x >> 3;          // 0..79, consecutive on XCD
    const int ksix = xcd + 8 * (j / NBB);      // k-slice, XCD-constant per sweep
    const int bb   = j % NBB;                  // row-block, consecutive on XCD
    const int i0   = bb * MA;                  // mult of 256 -> sigma uses local row

    __shared__ __align__(16) char lds[2 * TILEB];   // 48 KB
    __shared__ float bins[W];
    if (tid < W) bins[tid] = 0.f;

    const int n    = lane & 15;
    const int quad = lane >> 4;
    const int d0   = 2 * wv;                   // wave's diagonal pair d0, d0+1
    // per-lane fragment base: row n, slot quad ^ sigma(n); tile row R=16s+n
    // adds s*1024. sigma(16s+n) == (n>>1)&3 because 8s % 4 == 0.
    const int fragoff = n * 64 + ((quad ^ ((n >> 1) & 3)) << 4);
    const int lr16 = lane * 16;

    float4v acc0 = {0.f, 0.f, 0.f, 0.f};
    float4v acc1 = {0.f, 0.f, 0.f, 0.f};

    // staging: wave wv owns rows [wv*96, wv*96+96); 6 x 1-KiB contiguous DMA
    #define STAGE(bi, cix)                                                     \
        {                                                                      \
            const char* sb = Y + ((size_t)(cix) * RPAD + i0 + wv * 96) * GRAN; \
            char* db = lds + (bi) * TILEB + wv * 96 * GRAN;                    \
            _Pragma("unroll")                                                  \
            for (int m = 0; m < 6; ++m)                                        \
                gload_lds16(sb + m * 1024 + lr16, db + m * 1024);              \
        }

    STAGE(0, ksix * CPB)                       // prologue

    #pragma unroll
    for (int it = 0; it < CPB; ++it) {
        const int cur = it & 1;
        if (it + 1 < CPB) {
            STAGE(cur ^ 1, ksix * CPB + it + 1)          // prefetch next
            asm volatile("s_waitcnt vmcnt(6)" ::: "memory");  // cur done
        } else {
            asm volatile("s_waitcnt vmcnt(0)" ::: "memory");
        }
        __builtin_amdgcn_s_barrier();          // all waves' cur tile ready

        const char* lb = lds + cur * TILEB + fragoff;
        short8 fbp = *(const short8*)(lb + d0 * 1024);       // B subblock d0
        #pragma unroll
        for (int a = 0; a < NA; ++a) {
            const short8 fav = *(const short8*)(lb + a * 1024);
            const short8 fbn = *(const short8*)(lb + (d0 + a + 1) * 1024);
            acc0 = __builtin_amdgcn_mfma_f32_16x16x32_bf16(fav, fbp, acc0, 0, 0, 0);
            acc1 = __builtin_amdgcn_mfma_f32_16x16x32_bf16(fav, fbn, acc1, 0, 0, 0);
            fbp = fbn;
        }

        __builtin_amdgcn_sched_barrier(0);     // reads stay on this side
        __builtin_amdgcn_s_barrier();          // cur reusable
    }
    #undef STAGE

    // epilogue: D[m][n] of diagonal d -> lag t = 16d + n - m  (m = quad*4 + p)
    #pragma unroll
    for (int p = 0; p < 4; ++p) {
        const int m  = quad * 4 + p;
        const int t0 = 16 * d0 + n - m;
        if (t0 >= 0 && t0 < W) atomicAdd(&bins[t0], acc0[p]);
        const int t1 = t0 + 16;
        if (t1 >= 0 && t1 < W) atomicAdd(&bins[t1], acc1[p]);
    }
    __syncthreads();
    if (tid < W) atomicAdd(&partial[xcd * W + tid], bins[tid]);
}

// ---------------------------------------------------------------------------
// Fallback (ws too small): R10 register-staging kernel, proven correct.
// ---------------------------------------------------------------------------
__global__ __launch_bounds__(256, 2)
void vacf_fb(const float* __restrict__ X, float* __restrict__ partial) {
    const int tid  = threadIdx.x;
    const int lane = tid & 63;
    const int wv   = tid >> 6;
    const int xcd  = blockIdx.x & 7;
    const int j    = blockIdx.x >> 3;
    const int ksix = xcd + 8 * (j / FB_NBB);
    const int bb   = j % FB_NBB;
    const int i0   = bb * FB_MA;
    const int ks   = ksix * (FB_CPB * FB_KB);
    const int ke   = (ks + FB_CPB * FB_KB < C_DIM) ? (ks + FB_CPB * FB_KB) : C_DIM;
    const int nit  = (ke - ks + FB_KB - 1) / FB_KB;

    __shared__ short buf[FB_SROWS * FB_LPAD];
    __shared__ float bins[W];
    if (tid < W) bins[tid] = 0.f;

    const int cp = tid & 7;
    const int r0 = tid >> 3;
    const int n    = lane & 15;
    const int quad = lane >> 4;
    const int d0   = 2 * wv;
    const short* fragbase = &buf[n * FB_LPAD + quad * 8];

    float4v acc0 = {0.f, 0.f, 0.f, 0.f};
    float4v acc1 = {0.f, 0.f, 0.f, 0.f};
    float4v pf[FB_NA];

    {
        #pragma unroll
        for (int s = 0; s < FB_NA; ++s) {
            const int row = i0 + r0 + 32 * s;
            const int col = ks + 4 * cp;
            pf[s] = (row < T_DIM) ? *(const float4v*)(X + (size_t)row * C_DIM + col)
                                  : (float4v){0.f, 0.f, 0.f, 0.f};
        }
    }

    #pragma unroll 1
    for (int it = 0; it < nit; ++it) {
        __syncthreads();
        #pragma unroll
        for (int s = 0; s < FB_NA; ++s) {
            short4v o;
            o[0] = f2bf(pf[s][0]); o[1] = f2bf(pf[s][1]);
            o[2] = f2bf(pf[s][2]); o[3] = f2bf(pf[s][3]);
            *(short4v*)&buf[(r0 + 32 * s) * FB_LPAD + 4 * cp] = o;
        }
        __syncthreads();

        if (it + 1 < nit) {
            const int k0 = ks + (it + 1) * FB_KB;
            const bool kfull = (k0 + FB_KB <= ke);
            #pragma unroll
            for (int s = 0; s < FB_NA; ++s) {
                const int row = i0 + r0 + 32 * s;
                const int col = k0 + 4 * cp;
                if ((row < T_DIM) & kfull) {
                    pf[s] = *(const float4v*)(X + (size_t)row * C_DIM + col);
                } else {
                    #pragma unroll
                    for (int e = 0; e < 4; ++e)
                        pf[s][e] = (row < T_DIM && col + e < ke)
                                     ? X[(size_t)row * C_DIM + col + e] : 0.f;
                }
            }
        }

        short8 fa[FB_NA], fb[8];
        #pragma unroll
        for (int a = 0; a < FB_NA; ++a)
            fa[a] = *(const short8*)(fragbase + 16 * a * FB_LPAD);
        #pragma unroll
        for (int u = 0; u < 8; ++u)
            fb[u] = *(const short8*)(fragbase + 16 * (d0 + u) * FB_LPAD);

        #pragma unroll
        for (int a = 0; a < FB_NA; ++a) {
            acc0 = __builtin_amdgcn_mfma_f32_16x16x32_bf16(fa[a], fb[a],     acc0, 0, 0, 0);
            acc1 = __builtin_amdgcn_mfma_f32_16x16x32_bf16(fa[a], fb[a + 1], acc1, 0, 0, 0);
        }
    }

    #pragma unroll
    for (int p = 0; p < 4; ++p) {
        const int m  = quad * 4 + p;
        const int t0 = 16 * d0 + n - m;
        if (t0 >= 0 && t0 < W) atomicAdd(&bins[t0], acc0[p]);
        const int t1 = t0 + 16;
        if (t1 >= 0 && t1 < W) atomicAdd(&bins[t1], acc1[p]);
    }
    __syncthreads();
    if (tid < W) atomicAdd(&partial[xcd * W + tid], bins[tid]);
}

__global__ void vacf_scale(const float* __restrict__ partial, float* __restrict__ out) {
    int t = threadIdx.x;
    if (t < W) {
        float s = 0.f;
        #pragma unroll
        for (int b = 0; b < NPART; ++b) s += partial[b * W + t];
        out[t] = s / ((float)(T_DIM - t) * (float)C_DIM);
    }
}

extern "C" void kernel_launch(void* const* d_in, const int* in_sizes, int n_in,
                              void* d_out, int out_size, void* d_ws, size_t ws_size,
                              hipStream_t stream) {
    const float* X = (const float*)d_in[0];
    float* out = (float*)d_out;
    float* ws  = (float*)d_ws;

    hipMemsetAsync(ws, 0, NPART * W * sizeof(float), stream);
    if (ws_size >= WS_NEED) {
        char* Y = (char*)d_ws + YOFF;
        vacf_relayout<<<(RPAD / 64) * 12, 256, 0, stream>>>(X, Y);
        vacf_main<<<NBB * KSPLIT, 256, 0, stream>>>(Y, ws);
    } else {
        vacf_fb<<<FB_NBB * FB_KSPLIT, 256, 0, stream>>>(X, ws);
    }
    vacf_scale<<<1, 128, 0, stream>>>(ws, out);
}